// Round 2
// baseline (522.998 us; speedup 1.0000x reference)
//
#include <hip/hip_runtime.h>

#define N_NODES 100000
#define N_EDGES 1600000
#define F_DIM 48

// ---------------- fallback (round-1) path ----------------
__global__ void zero_out_kernel(float4* __restrict__ out, int n_vec4) {
    int i = blockIdx.x * blockDim.x + threadIdx.x;
    if (i < n_vec4) out[i] = make_float4(0.f, 0.f, 0.f, 0.f);
}

__global__ void scatter_atomic_kernel(const float* __restrict__ x,
                                      const float* __restrict__ w,
                                      const int* __restrict__ rows,
                                      const int* __restrict__ cols,
                                      const float* __restrict__ vals,
                                      float* __restrict__ out) {
    int tid = blockIdx.x * blockDim.x + threadIdx.x;
    int edge = tid >> 4;
    int l = tid & 15;
    if (edge >= N_EDGES) return;
    int col = cols[edge];
    int row = rows[edge];
    float val = vals[edge];
    const float* __restrict__ xr = x + (size_t)col * F_DIM;
    float* __restrict__ orow = out + (size_t)row * F_DIM;
#pragma unroll
    for (int k = 0; k < 3; ++k) {
        int f = l + k * 16;
        atomicAdd(&orow[f], val * xr[f] * w[f]);
    }
}

// ---------------- CSR counting-sort path ----------------

// K1: per-row degree counts (int atomics on 400KB L2-resident array)
__global__ void count_kernel(const int* __restrict__ rows, int* __restrict__ counts) {
    int e = blockIdx.x * blockDim.x + threadIdx.x;
    if (e < N_EDGES) atomicAdd(&counts[rows[e]], 1);
}

// K2: single-block exclusive scan of counts[0..N-1] -> offsets[0..N]
#define SCAN_T 1024
__global__ void scan_kernel(const int* __restrict__ counts, int* __restrict__ offsets) {
    const int CH = (N_NODES + SCAN_T - 1) / SCAN_T;  // 98
    int t = threadIdx.x;
    int base = t * CH;
    // pass A: local chunk sum
    int s = 0;
    for (int i = 0; i < CH; ++i) {
        int idx = base + i;
        if (idx < N_NODES) s += counts[idx];
    }
    // Hillis-Steele inclusive scan across 1024 threads
    __shared__ int sh[SCAN_T];
    sh[t] = s;
    __syncthreads();
    for (int off = 1; off < SCAN_T; off <<= 1) {
        int v = (t >= off) ? sh[t - off] : 0;
        __syncthreads();
        sh[t] += v;
        __syncthreads();
    }
    int excl = sh[t] - s;
    // pass B: write exclusive offsets for my chunk
    int run = excl;
    for (int i = 0; i < CH; ++i) {
        int idx = base + i;
        if (idx < N_NODES) {
            offsets[idx] = run;
            run += counts[idx];
        }
    }
    if (t == SCAN_T - 1) offsets[N_NODES] = sh[SCAN_T - 1];  // = N_EDGES
}

// K3: scatter (col,val) into row-sorted order
__global__ void permute_kernel(const int* __restrict__ rows,
                               const int* __restrict__ cols,
                               const float* __restrict__ vals,
                               int* __restrict__ cursor,
                               int* __restrict__ pcol,
                               float* __restrict__ pval) {
    int e = blockIdx.x * blockDim.x + threadIdx.x;
    if (e >= N_EDGES) return;
    int r = rows[e];
    int p = atomicAdd(&cursor[r], 1);
    pcol[p] = cols[e];
    pval[p] = vals[e];
}

// K4: per-node segmented accumulate. 16 lanes per node; lane l owns
// features {l, l+16, l+32} in registers. One coalesced 192B write per node,
// w[f] folded once at the end. No atomics.
__global__ void gather_accum_kernel(const float* __restrict__ x,
                                    const float* __restrict__ w,
                                    const int* __restrict__ offsets,
                                    const int* __restrict__ pcol,
                                    const float* __restrict__ pval,
                                    float* __restrict__ out) {
    int tid = blockIdx.x * blockDim.x + threadIdx.x;
    int node = tid >> 4;
    int l = tid & 15;
    if (node >= N_NODES) return;
    int beg = offsets[node];
    int end = offsets[node + 1];
    float a0 = 0.f, a1 = 0.f, a2 = 0.f;
    for (int j = beg; j < end; ++j) {
        int c = pcol[j];
        float v = pval[j];
        const float* __restrict__ xr = x + (size_t)c * F_DIM;
        a0 += v * xr[l];
        a1 += v * xr[l + 16];
        a2 += v * xr[l + 32];
    }
    float* __restrict__ orow = out + (size_t)node * F_DIM;
    orow[l]      = a0 * w[l];
    orow[l + 16] = a1 * w[l + 16];
    orow[l + 32] = a2 * w[l + 32];
}

extern "C" void kernel_launch(void* const* d_in, const int* in_sizes, int n_in,
                              void* d_out, int out_size, void* d_ws, size_t ws_size,
                              hipStream_t stream) {
    const float* x    = (const float*)d_in[0];
    const float* w    = (const float*)d_in[1];
    const int*   rows = (const int*)d_in[2];
    const int*   cols = (const int*)d_in[3];
    const float* vals = (const float*)d_in[4];
    float* out = (float*)d_out;

    // ws layout (256B-aligned blocks)
    auto align256 = [](size_t v) { return (v + 255) & ~(size_t)255; };
    size_t off_counts  = 0;
    size_t off_offsets = align256(off_counts + (size_t)N_NODES * 4);
    size_t off_cursor  = align256(off_offsets + (size_t)(N_NODES + 1) * 4);
    size_t off_pcol    = align256(off_cursor + (size_t)N_NODES * 4);
    size_t off_pval    = align256(off_pcol + (size_t)N_EDGES * 4);
    size_t needed      = align256(off_pval + (size_t)N_EDGES * 4);

    if (ws_size < needed) {
        // fallback: round-1 atomic path (branch on launch-constant -> same
        // work every call)
        int n_vec4 = (N_NODES * F_DIM) / 4;
        zero_out_kernel<<<(n_vec4 + 255) / 256, 256, 0, stream>>>((float4*)out, n_vec4);
        int total_threads = N_EDGES * 16;
        scatter_atomic_kernel<<<(total_threads + 255) / 256, 256, 0, stream>>>(
            x, w, rows, cols, vals, out);
        return;
    }

    char* ws = (char*)d_ws;
    int*   counts  = (int*)(ws + off_counts);
    int*   offsets = (int*)(ws + off_offsets);
    int*   cursor  = (int*)(ws + off_cursor);
    int*   pcol    = (int*)(ws + off_pcol);
    float* pval    = (float*)(ws + off_pval);

    // 1) zero counts
    hipMemsetAsync(counts, 0, (size_t)N_NODES * 4, stream);

    // 2) count degrees
    count_kernel<<<(N_EDGES + 255) / 256, 256, 0, stream>>>(rows, counts);

    // 3) exclusive scan -> offsets
    scan_kernel<<<1, SCAN_T, 0, stream>>>(counts, offsets);

    // 4) cursor = offsets ; permute edges into row-sorted order
    hipMemcpyAsync(cursor, offsets, (size_t)N_NODES * 4, hipMemcpyDeviceToDevice, stream);
    permute_kernel<<<(N_EDGES + 255) / 256, 256, 0, stream>>>(
        rows, cols, vals, cursor, pcol, pval);

    // 5) per-node gather-accumulate (writes every output element; no zero-init
    //    of d_out needed)
    int total_threads = N_NODES * 16;
    gather_accum_kernel<<<(total_threads + 255) / 256, 256, 0, stream>>>(
        x, w, offsets, pcol, pval, out);
}

// Round 3
// 312.992 us; speedup vs baseline: 1.6710x; 1.6710x over previous
//
#include <hip/hip_runtime.h>

#define N_NODES 100000
#define N_EDGES 1600000
#define F_DIM 48

#define SBS 256
#define SNB ((N_NODES + SBS - 1) / SBS)  // 391 blocks

// ---------------- fallback (round-1) path ----------------
__global__ void zero_out_kernel(float4* __restrict__ out, int n_vec4) {
    int i = blockIdx.x * blockDim.x + threadIdx.x;
    if (i < n_vec4) out[i] = make_float4(0.f, 0.f, 0.f, 0.f);
}

__global__ void scatter_atomic_kernel(const float* __restrict__ x,
                                      const float* __restrict__ w,
                                      const int* __restrict__ rows,
                                      const int* __restrict__ cols,
                                      const float* __restrict__ vals,
                                      float* __restrict__ out) {
    int tid = blockIdx.x * blockDim.x + threadIdx.x;
    int edge = tid >> 4;
    int l = tid & 15;
    if (edge >= N_EDGES) return;
    int col = cols[edge];
    int row = rows[edge];
    float val = vals[edge];
    const float* __restrict__ xr = x + (size_t)col * F_DIM;
    float* __restrict__ orow = out + (size_t)row * F_DIM;
#pragma unroll
    for (int k = 0; k < 3; ++k) {
        int f = l + k * 16;
        atomicAdd(&orow[f], val * xr[f] * w[f]);
    }
}

// ---------------- CSR counting-sort path ----------------

// K1: per-row degree counts (int atomics on 400KB L2-resident array)
__global__ void count_kernel(const int* __restrict__ rows, int* __restrict__ counts) {
    int e = blockIdx.x * blockDim.x + threadIdx.x;
    if (e < N_EDGES) atomicAdd(&counts[rows[e]], 1);
}

// K2a: per-block local exclusive scan; block sums to bsum
__global__ void scan_local_kernel(const int* __restrict__ counts,
                                  int* __restrict__ offsets,
                                  int* __restrict__ bsum) {
    __shared__ int sh[SBS];
    int idx = blockIdx.x * SBS + threadIdx.x;
    int v = (idx < N_NODES) ? counts[idx] : 0;
    sh[threadIdx.x] = v;
    __syncthreads();
    for (int off = 1; off < SBS; off <<= 1) {
        int t = (threadIdx.x >= off) ? sh[threadIdx.x - off] : 0;
        __syncthreads();
        sh[threadIdx.x] += t;
        __syncthreads();
    }
    if (idx < N_NODES) offsets[idx] = sh[threadIdx.x] - v;  // local exclusive
    if (threadIdx.x == SBS - 1) bsum[blockIdx.x] = sh[SBS - 1];
}

// K2b: single small block scans the 391 block sums
__global__ void scan_bsum_kernel(const int* __restrict__ bsum,
                                 int* __restrict__ bbase,
                                 int* __restrict__ offsets) {
    __shared__ int sh[512];
    int t = threadIdx.x;
    int v = (t < SNB) ? bsum[t] : 0;
    sh[t] = v;
    __syncthreads();
    for (int off = 1; off < 512; off <<= 1) {
        int u = (t >= off) ? sh[t - off] : 0;
        __syncthreads();
        sh[t] += u;
        __syncthreads();
    }
    if (t < SNB) bbase[t] = sh[t] - v;
    if (t == 511) offsets[N_NODES] = sh[511];  // total == N_EDGES
}

// K2c: add block bases; also materialize cursor copy
__global__ void scan_add_kernel(int* __restrict__ offsets,
                                const int* __restrict__ bbase,
                                int* __restrict__ cursor) {
    int idx = blockIdx.x * SBS + threadIdx.x;
    if (idx < N_NODES) {
        int o = offsets[idx] + bbase[blockIdx.x];
        offsets[idx] = o;
        cursor[idx] = o;
    }
}

// K3: scatter (col,val) into row-sorted order
__global__ void permute_kernel(const int* __restrict__ rows,
                               const int* __restrict__ cols,
                               const float* __restrict__ vals,
                               int* __restrict__ cursor,
                               int* __restrict__ pcol,
                               float* __restrict__ pval) {
    int e = blockIdx.x * blockDim.x + threadIdx.x;
    if (e >= N_EDGES) return;
    int r = rows[e];
    int p = atomicAdd(&cursor[r], 1);
    pcol[p] = cols[e];
    pval[p] = vals[e];
}

// K4: per-node segmented accumulate. 16 lanes per node; lane l owns
// features {l, l+16, l+32} in registers. Unrolled x2 for gather ILP.
__global__ void gather_accum_kernel(const float* __restrict__ x,
                                    const float* __restrict__ w,
                                    const int* __restrict__ offsets,
                                    const int* __restrict__ pcol,
                                    const float* __restrict__ pval,
                                    float* __restrict__ out) {
    int tid = blockIdx.x * blockDim.x + threadIdx.x;
    int node = tid >> 4;
    int l = tid & 15;
    if (node >= N_NODES) return;
    int beg = offsets[node];
    int end = offsets[node + 1];
    float a0 = 0.f, a1 = 0.f, a2 = 0.f;
    int j = beg;
    for (; j + 1 < end; j += 2) {
        int c0 = pcol[j], c1 = pcol[j + 1];
        float v0 = pval[j], v1 = pval[j + 1];
        const float* __restrict__ x0 = x + (size_t)c0 * F_DIM;
        const float* __restrict__ x1 = x + (size_t)c1 * F_DIM;
        a0 += v0 * x0[l]      + v1 * x1[l];
        a1 += v0 * x0[l + 16] + v1 * x1[l + 16];
        a2 += v0 * x0[l + 32] + v1 * x1[l + 32];
    }
    if (j < end) {
        int c = pcol[j];
        float v = pval[j];
        const float* __restrict__ xr = x + (size_t)c * F_DIM;
        a0 += v * xr[l];
        a1 += v * xr[l + 16];
        a2 += v * xr[l + 32];
    }
    float* __restrict__ orow = out + (size_t)node * F_DIM;
    orow[l]      = a0 * w[l];
    orow[l + 16] = a1 * w[l + 16];
    orow[l + 32] = a2 * w[l + 32];
}

extern "C" void kernel_launch(void* const* d_in, const int* in_sizes, int n_in,
                              void* d_out, int out_size, void* d_ws, size_t ws_size,
                              hipStream_t stream) {
    const float* x    = (const float*)d_in[0];
    const float* w    = (const float*)d_in[1];
    const int*   rows = (const int*)d_in[2];
    const int*   cols = (const int*)d_in[3];
    const float* vals = (const float*)d_in[4];
    float* out = (float*)d_out;

    // ws layout (256B-aligned blocks)
    auto align256 = [](size_t v) { return (v + 255) & ~(size_t)255; };
    size_t off_counts  = 0;
    size_t off_offsets = align256(off_counts + (size_t)N_NODES * 4);
    size_t off_cursor  = align256(off_offsets + (size_t)(N_NODES + 1) * 4);
    size_t off_pcol    = align256(off_cursor + (size_t)N_NODES * 4);
    size_t off_pval    = align256(off_pcol + (size_t)N_EDGES * 4);
    size_t off_bsum    = align256(off_pval + (size_t)N_EDGES * 4);
    size_t off_bbase   = align256(off_bsum + (size_t)SNB * 4);
    size_t needed      = align256(off_bbase + (size_t)SNB * 4);

    if (ws_size < needed) {
        // fallback: atomic path (branch on launch-constant -> same work every call)
        int n_vec4 = (N_NODES * F_DIM) / 4;
        zero_out_kernel<<<(n_vec4 + 255) / 256, 256, 0, stream>>>((float4*)out, n_vec4);
        int total_threads = N_EDGES * 16;
        scatter_atomic_kernel<<<(total_threads + 255) / 256, 256, 0, stream>>>(
            x, w, rows, cols, vals, out);
        return;
    }

    char* ws = (char*)d_ws;
    int*   counts  = (int*)(ws + off_counts);
    int*   offsets = (int*)(ws + off_offsets);
    int*   cursor  = (int*)(ws + off_cursor);
    int*   pcol    = (int*)(ws + off_pcol);
    float* pval    = (float*)(ws + off_pval);
    int*   bsum    = (int*)(ws + off_bsum);
    int*   bbase   = (int*)(ws + off_bbase);

    // 1) zero counts
    hipMemsetAsync(counts, 0, (size_t)N_NODES * 4, stream);

    // 2) count degrees
    count_kernel<<<(N_EDGES + 255) / 256, 256, 0, stream>>>(rows, counts);

    // 3) hierarchical exclusive scan -> offsets (+cursor copy)
    scan_local_kernel<<<SNB, SBS, 0, stream>>>(counts, offsets, bsum);
    scan_bsum_kernel<<<1, 512, 0, stream>>>(bsum, bbase, offsets);
    scan_add_kernel<<<SNB, SBS, 0, stream>>>(offsets, bbase, cursor);

    // 4) permute edges into row-sorted order
    permute_kernel<<<(N_EDGES + 255) / 256, 256, 0, stream>>>(
        rows, cols, vals, cursor, pcol, pval);

    // 5) per-node gather-accumulate (writes every output element)
    int total_threads = N_NODES * 16;
    gather_accum_kernel<<<(total_threads + 255) / 256, 256, 0, stream>>>(
        x, w, offsets, pcol, pval, out);
}

// Round 4
// 311.641 us; speedup vs baseline: 1.6782x; 1.0043x over previous
//
#include <hip/hip_runtime.h>

#define N_NODES 100000
#define N_EDGES 1600000
#define F_DIM 48

#define SBS 256
#define SNB ((N_NODES + SBS - 1) / SBS)  // 391 blocks

// ---------------- fallback (round-1) path ----------------
__global__ void zero_out_kernel(float4* __restrict__ out, int n_vec4) {
    int i = blockIdx.x * blockDim.x + threadIdx.x;
    if (i < n_vec4) out[i] = make_float4(0.f, 0.f, 0.f, 0.f);
}

__global__ void scatter_atomic_kernel(const float* __restrict__ x,
                                      const float* __restrict__ w,
                                      const int* __restrict__ rows,
                                      const int* __restrict__ cols,
                                      const float* __restrict__ vals,
                                      float* __restrict__ out) {
    int tid = blockIdx.x * blockDim.x + threadIdx.x;
    int edge = tid >> 4;
    int l = tid & 15;
    if (edge >= N_EDGES) return;
    int col = cols[edge];
    int row = rows[edge];
    float val = vals[edge];
    const float* __restrict__ xr = x + (size_t)col * F_DIM;
    float* __restrict__ orow = out + (size_t)row * F_DIM;
#pragma unroll
    for (int k = 0; k < 3; ++k) {
        int f = l + k * 16;
        atomicAdd(&orow[f], val * xr[f] * w[f]);
    }
}

// ---------------- CSR counting-sort path ----------------

// K1: per-row degree counts (int atomics on 400KB L2-resident array)
__global__ void count_kernel(const int* __restrict__ rows, int* __restrict__ counts) {
    int e = blockIdx.x * blockDim.x + threadIdx.x;
    if (e < N_EDGES) atomicAdd(&counts[rows[e]], 1);
}

// K2a: per-block local exclusive scan; block sums to bsum
__global__ void scan_local_kernel(const int* __restrict__ counts,
                                  int* __restrict__ offsets,
                                  int* __restrict__ bsum) {
    __shared__ int sh[SBS];
    int idx = blockIdx.x * SBS + threadIdx.x;
    int v = (idx < N_NODES) ? counts[idx] : 0;
    sh[threadIdx.x] = v;
    __syncthreads();
    for (int off = 1; off < SBS; off <<= 1) {
        int t = (threadIdx.x >= off) ? sh[threadIdx.x - off] : 0;
        __syncthreads();
        sh[threadIdx.x] += t;
        __syncthreads();
    }
    if (idx < N_NODES) offsets[idx] = sh[threadIdx.x] - v;  // local exclusive
    if (threadIdx.x == SBS - 1) bsum[blockIdx.x] = sh[SBS - 1];
}

// K2b: single small block scans the 391 block sums
__global__ void scan_bsum_kernel(const int* __restrict__ bsum,
                                 int* __restrict__ bbase,
                                 int* __restrict__ offsets) {
    __shared__ int sh[512];
    int t = threadIdx.x;
    int v = (t < SNB) ? bsum[t] : 0;
    sh[t] = v;
    __syncthreads();
    for (int off = 1; off < 512; off <<= 1) {
        int u = (t >= off) ? sh[t - off] : 0;
        __syncthreads();
        sh[t] += u;
        __syncthreads();
    }
    if (t < SNB) bbase[t] = sh[t] - v;
    if (t == 511) offsets[N_NODES] = sh[511];  // total == N_EDGES
}

// K2c: add block bases; also materialize cursor copy
__global__ void scan_add_kernel(int* __restrict__ offsets,
                                const int* __restrict__ bbase,
                                int* __restrict__ cursor) {
    int idx = blockIdx.x * SBS + threadIdx.x;
    if (idx < N_NODES) {
        int o = offsets[idx] + bbase[blockIdx.x];
        offsets[idx] = o;
        cursor[idx] = o;
    }
}

// K3: scatter packed (col,val) into row-sorted order — single 8B write/edge
__global__ void permute_kernel(const int* __restrict__ rows,
                               const int* __restrict__ cols,
                               const float* __restrict__ vals,
                               int* __restrict__ cursor,
                               int2* __restrict__ pcv) {
    int e = blockIdx.x * blockDim.x + threadIdx.x;
    if (e >= N_EDGES) return;
    int r = rows[e];
    int p = atomicAdd(&cursor[r], 1);
    pcv[p] = make_int2(cols[e], __float_as_int(vals[e]));
}

// K4: per-node segmented accumulate. 16 lanes per node; lane l owns
// features {l, l+16, l+32} in registers. Unrolled x4 for gather ILP.
__global__ void gather_accum_kernel(const float* __restrict__ x,
                                    const float* __restrict__ w,
                                    const int* __restrict__ offsets,
                                    const int2* __restrict__ pcv,
                                    float* __restrict__ out) {
    int tid = blockIdx.x * blockDim.x + threadIdx.x;
    int node = tid >> 4;
    int l = tid & 15;
    if (node >= N_NODES) return;
    int beg = offsets[node];
    int end = offsets[node + 1];
    float a0 = 0.f, a1 = 0.f, a2 = 0.f;
    int j = beg;
    for (; j + 3 < end; j += 4) {
        int2 e0 = pcv[j], e1 = pcv[j + 1], e2 = pcv[j + 2], e3 = pcv[j + 3];
        const float* __restrict__ x0 = x + (size_t)e0.x * F_DIM;
        const float* __restrict__ x1 = x + (size_t)e1.x * F_DIM;
        const float* __restrict__ x2 = x + (size_t)e2.x * F_DIM;
        const float* __restrict__ x3 = x + (size_t)e3.x * F_DIM;
        float v0 = __int_as_float(e0.y), v1 = __int_as_float(e1.y);
        float v2 = __int_as_float(e2.y), v3 = __int_as_float(e3.y);
        a0 += v0 * x0[l]      + v1 * x1[l]      + v2 * x2[l]      + v3 * x3[l];
        a1 += v0 * x0[l + 16] + v1 * x1[l + 16] + v2 * x2[l + 16] + v3 * x3[l + 16];
        a2 += v0 * x0[l + 32] + v1 * x1[l + 32] + v2 * x2[l + 32] + v3 * x3[l + 32];
    }
    for (; j < end; ++j) {
        int2 e = pcv[j];
        float v = __int_as_float(e.y);
        const float* __restrict__ xr = x + (size_t)e.x * F_DIM;
        a0 += v * xr[l];
        a1 += v * xr[l + 16];
        a2 += v * xr[l + 32];
    }
    float* __restrict__ orow = out + (size_t)node * F_DIM;
    orow[l]      = a0 * w[l];
    orow[l + 16] = a1 * w[l + 16];
    orow[l + 32] = a2 * w[l + 32];
}

extern "C" void kernel_launch(void* const* d_in, const int* in_sizes, int n_in,
                              void* d_out, int out_size, void* d_ws, size_t ws_size,
                              hipStream_t stream) {
    const float* x    = (const float*)d_in[0];
    const float* w    = (const float*)d_in[1];
    const int*   rows = (const int*)d_in[2];
    const int*   cols = (const int*)d_in[3];
    const float* vals = (const float*)d_in[4];
    float* out = (float*)d_out;

    // ws layout (256B-aligned blocks)
    auto align256 = [](size_t v) { return (v + 255) & ~(size_t)255; };
    size_t off_counts  = 0;
    size_t off_offsets = align256(off_counts + (size_t)N_NODES * 4);
    size_t off_cursor  = align256(off_offsets + (size_t)(N_NODES + 1) * 4);
    size_t off_pcv     = align256(off_cursor + (size_t)N_NODES * 4);
    size_t off_bsum    = align256(off_pcv + (size_t)N_EDGES * 8);
    size_t off_bbase   = align256(off_bsum + (size_t)SNB * 4);
    size_t needed      = align256(off_bbase + (size_t)SNB * 4);

    if (ws_size < needed) {
        // fallback: atomic path (branch on launch-constant -> same work every call)
        int n_vec4 = (N_NODES * F_DIM) / 4;
        zero_out_kernel<<<(n_vec4 + 255) / 256, 256, 0, stream>>>((float4*)out, n_vec4);
        int total_threads = N_EDGES * 16;
        scatter_atomic_kernel<<<(total_threads + 255) / 256, 256, 0, stream>>>(
            x, w, rows, cols, vals, out);
        return;
    }

    char* ws = (char*)d_ws;
    int*   counts  = (int*)(ws + off_counts);
    int*   offsets = (int*)(ws + off_offsets);
    int*   cursor  = (int*)(ws + off_cursor);
    int2*  pcv     = (int2*)(ws + off_pcv);
    int*   bsum    = (int*)(ws + off_bsum);
    int*   bbase   = (int*)(ws + off_bbase);

    // 1) zero counts
    hipMemsetAsync(counts, 0, (size_t)N_NODES * 4, stream);

    // 2) count degrees
    count_kernel<<<(N_EDGES + 255) / 256, 256, 0, stream>>>(rows, counts);

    // 3) hierarchical exclusive scan -> offsets (+cursor copy)
    scan_local_kernel<<<SNB, SBS, 0, stream>>>(counts, offsets, bsum);
    scan_bsum_kernel<<<1, 512, 0, stream>>>(bsum, bbase, offsets);
    scan_add_kernel<<<SNB, SBS, 0, stream>>>(offsets, bbase, cursor);

    // 4) permute edges into row-sorted order (packed 8B writes)
    permute_kernel<<<(N_EDGES + 255) / 256, 256, 0, stream>>>(
        rows, cols, vals, cursor, pcv);

    // 5) per-node gather-accumulate (writes every output element)
    int total_threads = N_NODES * 16;
    gather_accum_kernel<<<(total_threads + 255) / 256, 256, 0, stream>>>(
        x, w, offsets, pcv, out);
}